// Round 1
// baseline (130.192 us; speedup 1.0000x reference)
//
#include <hip/hip_runtime.h>

// DiscriminativeLoss: data [32, 512, 1024] f32 (D-planar), labels [512,1024] i32 in [0,16)
// out: scalar f32 loss.
//
// ws float layout:
//   [0, 512)    sums[k*32 + d]
//   [512, 528)  counts[k]
//   [528, 1040) centers_t[d*16 + k]   (transposed for broadcast-friendly LDS reads)

constexpr int KC = 16;
constexpr int DD = 32;
constexpr int NN = 512 * 1024;
constexpr int N4 = NN / 4;            // 131072 float4 groups per d-plane
constexpr int CHUNKS = 16;
constexpr int GROUPS_PER_CHUNK = N4 / CHUNKS;   // 8192
constexpr int K1_ITERS = GROUPS_PER_CHUNK / 256; // 32

__global__ __launch_bounds__(256) void k1_sums(const float4* __restrict__ data4,
                                               const int4* __restrict__ lab4,
                                               float* __restrict__ ws) {
    const int tid = threadIdx.x;
    const int d = blockIdx.y;
    const bool doCnt = (d == 0);

    // Per-thread private accumulator rows (stride 17 to spread LDS banks).
    __shared__ float acc[256 * 17];
    __shared__ float cnt[256 * 17];
    float* arow = acc + tid * 17;
    float* crow = cnt + tid * 17;
#pragma unroll
    for (int k = 0; k < KC; ++k) { arow[k] = 0.f; crow[k] = 0.f; }

    const int base = blockIdx.x * GROUPS_PER_CHUNK + tid;
    const float4* dplane = data4 + (size_t)d * N4;

    for (int it = 0; it < K1_ITERS; ++it) {
        const int g = base + it * 256;
        const float4 v = dplane[g];
        const int4 lb = lab4[g];
        arow[lb.x] += v.x;
        arow[lb.y] += v.y;
        arow[lb.z] += v.z;
        arow[lb.w] += v.w;
        if (doCnt) {
            crow[lb.x] += 1.f;
            crow[lb.y] += 1.f;
            crow[lb.z] += 1.f;
            crow[lb.w] += 1.f;
        }
    }
    __syncthreads();

    // Tree-reduce the 256 rows.
    for (int off = 128; off > 0; off >>= 1) {
        if (tid < off) {
#pragma unroll
            for (int k = 0; k < KC; ++k) acc[tid * 17 + k] += acc[(tid + off) * 17 + k];
            if (doCnt) {
#pragma unroll
                for (int k = 0; k < KC; ++k) cnt[tid * 17 + k] += cnt[(tid + off) * 17 + k];
            }
        }
        __syncthreads();
    }
    if (tid < KC) {
        atomicAdd(&ws[tid * DD + d], acc[tid]);          // acc row 0, cluster tid
        if (doCnt) atomicAdd(&ws[512 + tid], cnt[tid]);
    }
}

__global__ __launch_bounds__(256) void k2_centers(float* __restrict__ ws,
                                                  float* __restrict__ out) {
    __shared__ float cent[KC][DD + 1];
    __shared__ float red[256];
    const int tid = threadIdx.x;

    for (int idx = tid; idx < KC * DD; idx += 256) {
        const int k = idx >> 5, d = idx & 31;
        const float c = ws[idx] / ws[512 + k];
        cent[k][d] = c;
        ws[528 + d * KC + k] = c;   // centers_t for pass 2
    }
    __syncthreads();

    // 256 threads = 256 ordered pairs (i, j).
    const int i = tid >> 4, j = tid & 15;
    float sq = 0.f;
#pragma unroll
    for (int d = 0; d < DD; ++d) {
        const float df = cent[i][d] - cent[j][d];
        sq += df * df;
    }
    float val = 0.f;
    if (i != j) {
        const float pd = sqrtf(sq);
        const float t = fmaxf(3.0f - pd, 0.f);   // 2*DELTA_DIST = 3.0
        val = t * t * (1.0f / (KC * (KC - 1)));  // dist_term contribution
    } else {
        float s2 = 0.f;
#pragma unroll
        for (int d = 0; d < DD; ++d) s2 += cent[i][d] * cent[i][d];
        val = sqrtf(s2) * (0.001f / KC);         // reg_term contribution
    }
    red[tid] = val;
    __syncthreads();
    for (int off = 128; off > 0; off >>= 1) {
        if (tid < off) red[tid] += red[tid + off];
        __syncthreads();
    }
    if (tid == 0) out[0] = red[0];               // plain store; k3 atomicAdds on top
}

__global__ __launch_bounds__(256) void k3_var(const float4* __restrict__ data4,
                                              const int4* __restrict__ lab4,
                                              const float* __restrict__ ws,
                                              float* __restrict__ out) {
    __shared__ float ct[DD * KC];
    const int tid = threadIdx.x;
    for (int idx = tid; idx < DD * KC; idx += 256) ct[idx] = ws[528 + idx];
    __syncthreads();

    const int g = blockIdx.x * 256 + tid;        // one float4 group of points
    const int4 lb = lab4[g];
    float s0 = 0.f, s1 = 0.f, s2 = 0.f, s3 = 0.f;
#pragma unroll 8
    for (int d = 0; d < DD; ++d) {
        const float4 v = data4[(size_t)d * N4 + g];
        const float* ctd = ct + d * KC;
        const float d0 = ctd[lb.x] - v.x; s0 += d0 * d0;
        const float d1 = ctd[lb.y] - v.y; s1 += d1 * d1;
        const float d2 = ctd[lb.z] - v.z; s2 += d2 * d2;
        const float d3 = ctd[lb.w] - v.w; s3 += d3 * d3;
    }
    const float h0 = fmaxf(sqrtf(s0) - 0.5f, 0.f);
    const float h1 = fmaxf(sqrtf(s1) - 0.5f, 0.f);
    const float h2 = fmaxf(sqrtf(s2) - 0.5f, 0.f);
    const float h3 = fmaxf(sqrtf(s3) - 0.5f, 0.f);
    float lsum = h0 * h0 + h1 * h1 + h2 * h2 + h3 * h3;

    // wave (64) shuffle reduce, then cross-wave via LDS
#pragma unroll
    for (int off = 32; off > 0; off >>= 1) lsum += __shfl_down(lsum, off);
    __shared__ float wred[4];
    if ((tid & 63) == 0) wred[tid >> 6] = lsum;
    __syncthreads();
    if (tid == 0) {
        const float s = wred[0] + wred[1] + wred[2] + wred[3];
        atomicAdd(out, s * (1.0f / KC));
    }
}

extern "C" void kernel_launch(void* const* d_in, const int* in_sizes, int n_in,
                              void* d_out, int out_size, void* d_ws, size_t ws_size,
                              hipStream_t stream) {
    const float4* data4 = (const float4*)d_in[0];
    const int4* lab4 = (const int4*)d_in[1];
    float* out = (float*)d_out;
    float* ws = (float*)d_ws;

    // zero sums + counts region (ws is poisoned 0xAA before every call)
    hipMemsetAsync(ws, 0, 528 * sizeof(float), stream);

    k1_sums<<<dim3(CHUNKS, DD), 256, 0, stream>>>(data4, (const int4*)lab4, ws);
    k2_centers<<<1, 256, 0, stream>>>(ws, out);
    k3_var<<<512, 256, 0, stream>>>(data4, (const int4*)lab4, ws, out);
}